// Round 10
// baseline (470.782 us; speedup 1.0000x reference)
//
#include <hip/hip_runtime.h>
#include <math.h>

#define NSAMP 1024
#define DIM   64
#define NLAYER 3

#define JC 64                        // j rows per chunk (LDS tile)
#define JS (NSAMP / JC)              // 16 j-chunks
#define NT 64                        // n rows per block tile
#define RT 4                         // n rows per thread
#define NTILES (NSAMP / NT)          // 16 n-tiles
#define NBLK (NTILES * JS * NLAYER)  // 768 pair blocks

#define MAGIC_HI 0x5AFE600Du

// workspace layout (float units)
#define MU_OFF   0
#define INV_OFF  (NLAYER * NSAMP * DIM)        // 196608
#define SLOT_F   (2 * NLAYER * NSAMP * DIM)    // u64 slots start here (8B-aligned)
#define WS_REQ   ((size_t)SLOT_F * sizeof(float) + NBLK * sizeof(unsigned long long))
#define DUMP_F   (4 * 1024 * 1024)             // probe dump region (16MB offset)
#define WS_PROBE ((size_t)(DUMP_F + 16384) * sizeof(float))

typedef unsigned long long u64;

// ---------------------------------------------------------------------------
// REAL PATH dispatch 1: head precompute (proven round-6 kernel, verbatim)
__global__ __launch_bounds__(256) void ib_head(
    const float* __restrict__ f1, const float* __restrict__ f2,
    const float* __restrict__ f3,
    const float* __restrict__ W_mu, const float* __restrict__ b_mu,
    const float* __restrict__ W_var, const float* __restrict__ b_var,
    float* __restrict__ ws)
{
    const int layer = blockIdx.y;
    const float* __restrict__ fs_p = (layer == 0) ? f1 : (layer == 1) ? f2 : f3;

    const int tid = threadIdx.x;
    const int d   = tid & 63;
    const int nl  = tid >> 6;
    const int n   = blockIdx.x * 4 + nl;

    __shared__ float fs[4][DIM];
    fs[nl][d] = fs_p[n * DIM + d];
    __syncthreads();

    const float4* __restrict__ wm = (const float4*)(W_mu + (layer * DIM + d) * DIM);
    const float4* __restrict__ wv = (const float4*)(W_var + (layer * DIM + d) * DIM);
    float am = 0.f, av = 0.f;
#pragma unroll
    for (int k = 0; k < DIM / 4; ++k) {
        const float4 m4 = wm[k];
        const float4 v4 = wv[k];
        const float f0 = fs[nl][k * 4 + 0];
        const float f1v = fs[nl][k * 4 + 1];
        const float f2v = fs[nl][k * 4 + 2];
        const float f3v = fs[nl][k * 4 + 3];
        am = fmaf(f0, m4.x, am); am = fmaf(f1v, m4.y, am);
        am = fmaf(f2v, m4.z, am); am = fmaf(f3v, m4.w, am);
        av = fmaf(f0, v4.x, av); av = fmaf(f1v, v4.y, av);
        av = fmaf(f2v, v4.z, av); av = fmaf(f3v, v4.w, av);
    }
    const float mu = am + b_mu[layer * DIM + d];
    const float x  = av + b_var[layer * DIM + d];
    const float sp  = fmaxf(x, 0.f) + log1pf(expf(-fabsf(x)));
    const float var = sp * 0.1f + 1e-6f;

    const int o = (layer * NSAMP + n) * DIM + d;
    ws[MU_OFF + o]  = mu;
    ws[INV_OFF + o] = 1.0f / var;
}

// ---------------------------------------------------------------------------
// REAL PATH dispatch 2: pairwise + in-kernel final (proven round-6, verbatim)
__global__ __launch_bounds__(256) void ib_pairf(
    const float* __restrict__ fea0, const float* __restrict__ fea1,
    const float* __restrict__ fea2,
    const float* __restrict__ ws, u64* __restrict__ slots,
    float* __restrict__ out)
{
    const int b     = blockIdx.x;          // 0..767
    const int layer = b >> 8;
    const int sub   = b & 255;
    const int ntile = sub & 15;
    const int jc    = sub >> 4;
    const int tid   = threadIdx.x;

    const float* __restrict__ fr_p =
        (layer == 0) ? fea0 : (layer == 1) ? fea1 : fea2;

    const int q  = tid & 15;
    const int rg = tid >> 4;
    const int n0 = ntile * NT + rg * RT;
    const int d0 = q * 4;

    __shared__ float4 fr[JC][DIM / 4];   // 16 KB
    __shared__ float  wsum[4];

    const float4* __restrict__ src = (const float4*)(fr_p + jc * JC * DIM);
#pragma unroll
    for (int t = 0; t < 4; ++t)
        ((float4*)fr)[tid + t * 256] = src[tid + t * 256];

    const float4* __restrict__ mup =
        (const float4*)(ws + MU_OFF + (layer * NSAMP + n0) * DIM + d0);
    float4 mu4[RT];
#pragma unroll
    for (int r = 0; r < RT; ++r) mu4[r] = mup[r * (DIM / 4)];

    float4 ps[RT];
#pragma unroll
    for (int r = 0; r < RT; ++r) ps[r] = make_float4(0.f, 0.f, 0.f, 0.f);

    __syncthreads();
#pragma unroll 8
    for (int j = 0; j < JC; ++j) {
        const float4 f = fr[j][q];
#pragma unroll
        for (int r = 0; r < RT; ++r) {
            ps[r].x += fabsf(f.x - mu4[r].x);
            ps[r].y += fabsf(f.y - mu4[r].y);
            ps[r].z += fabsf(f.z - mu4[r].z);
            ps[r].w += fabsf(f.w - mu4[r].w);
        }
    }

    const float4* __restrict__ ivp =
        (const float4*)(ws + INV_OFF + (layer * NSAMP + n0) * DIM + d0);
    const float inv_n = 1.0f / (float)NSAMP;
    float s = 0.f;
    if (jc == 0) {
        const float4* __restrict__ fsp = (const float4*)(fr_p + n0 * DIM + d0);
#pragma unroll
        for (int r = 0; r < RT; ++r) {
            const float4 iv = ivp[r * (DIM / 4)];
            const float4 a  = fsp[r * (DIM / 4)];
            s += (ps[r].x * inv_n - fabsf(mu4[r].x - a.x)) * iv.x;
            s += (ps[r].y * inv_n - fabsf(mu4[r].y - a.y)) * iv.y;
            s += (ps[r].z * inv_n - fabsf(mu4[r].z - a.z)) * iv.z;
            s += (ps[r].w * inv_n - fabsf(mu4[r].w - a.w)) * iv.w;
        }
    } else {
#pragma unroll
        for (int r = 0; r < RT; ++r) {
            const float4 iv = ivp[r * (DIM / 4)];
            s += ps[r].x * inv_n * iv.x;
            s += ps[r].y * inv_n * iv.y;
            s += ps[r].z * inv_n * iv.z;
            s += ps[r].w * inv_n * iv.w;
        }
    }

#pragma unroll
    for (int off = 32; off > 0; off >>= 1)
        s += __shfl_down(s, off, 64);
    if ((tid & 63) == 0) wsum[tid >> 6] = s;
    __syncthreads();

    if (tid == 0) {
        const float p = wsum[0] + wsum[1] + wsum[2] + wsum[3];
        const u64 v = ((u64)MAGIC_HI << 32) | (u64)__float_as_uint(p);
        __hip_atomic_store(&slots[b], v, __ATOMIC_RELAXED,
                           __HIP_MEMORY_SCOPE_AGENT);
    }

    if (b == 0) {
        __syncthreads();
        u64 v[3];
#pragma unroll
        for (int t = 0; t < 3; ++t) {
            u64* slot = &slots[tid + t * 256];
            for (;;) {
                const u64 x = __hip_atomic_load(slot, __ATOMIC_RELAXED,
                                                __HIP_MEMORY_SCOPE_AGENT);
                if ((unsigned)(x >> 32) == MAGIC_HI) { v[t] = x; break; }
                __builtin_amdgcn_s_sleep(1);
            }
        }
#pragma unroll
        for (int t = 0; t < 3; ++t)
            __hip_atomic_store(&slots[tid + t * 256], 0ull, __ATOMIC_RELAXED,
                               __HIP_MEMORY_SCOPE_AGENT);
        float s2 = __uint_as_float((unsigned)v[0])
                 + __uint_as_float((unsigned)v[1])
                 + __uint_as_float((unsigned)v[2]);
#pragma unroll
        for (int off = 32; off > 0; off >>= 1)
            s2 += __shfl_down(s2, off, 64);
        if ((tid & 63) == 0) wsum[tid >> 6] = s2;
        __syncthreads();
        if (tid == 0)
            out[0] = (wsum[0] + wsum[1] + wsum[2] + wsum[3]) * inv_n;
    }
}

// ===========================================================================
// PROBES — amplified, isolated phases. Results dumped to ws (never read).
// Outer loops are '#pragma unroll 1' with iteration-dependent indexing so the
// compiler cannot CSE/hoist across repeats.
// ===========================================================================

// P1: full pair-loop replica (stage + LDS reads + 32 VALU/j), x8
__global__ __launch_bounds__(256) void probe_pair(
    const float* __restrict__ fea0, const float* __restrict__ fea1,
    const float* __restrict__ fea2,
    const float* __restrict__ ws, float* __restrict__ dump)
{
    const int b = blockIdx.x, layer = b >> 8, sub = b & 255;
    const int ntile = sub & 15, jc = sub >> 4, tid = threadIdx.x;
    const float* __restrict__ fr_p =
        (layer == 0) ? fea0 : (layer == 1) ? fea1 : fea2;
    const int q = tid & 15, rg = tid >> 4;
    const int n0 = ntile * NT + rg * RT, d0 = q * 4;

    __shared__ float4 fr[JC][DIM / 4];
    __shared__ float wsum[4];

    const float4* __restrict__ src = (const float4*)(fr_p + jc * JC * DIM);
#pragma unroll
    for (int t = 0; t < 4; ++t)
        ((float4*)fr)[tid + t * 256] = src[tid + t * 256];

    const float4* __restrict__ mup =
        (const float4*)(ws + MU_OFF + (layer * NSAMP + n0) * DIM + d0);
    float4 mu4[RT];
#pragma unroll
    for (int r = 0; r < RT; ++r) mu4[r] = mup[r * (DIM / 4)];
    float4 ps[RT];
#pragma unroll
    for (int r = 0; r < RT; ++r) ps[r] = make_float4(0.f, 0.f, 0.f, 0.f);

    __syncthreads();
#pragma unroll 1
    for (int it = 0; it < 8; ++it) {
#pragma unroll 8
        for (int j = 0; j < JC; ++j) {
            const float4 f = fr[(j + it * 9) & 63][q];
#pragma unroll
            for (int r = 0; r < RT; ++r) {
                ps[r].x += fabsf(f.x - mu4[r].x);
                ps[r].y += fabsf(f.y - mu4[r].y);
                ps[r].z += fabsf(f.z - mu4[r].z);
                ps[r].w += fabsf(f.w - mu4[r].w);
            }
        }
    }
    float s = 0.f;
#pragma unroll
    for (int r = 0; r < RT; ++r)
        s += ps[r].x + ps[r].y + ps[r].z + ps[r].w;
#pragma unroll
    for (int off = 32; off > 0; off >>= 1) s += __shfl_down(s, off, 64);
    if ((tid & 63) == 0) wsum[tid >> 6] = s;
    __syncthreads();
    if (tid == 0) dump[b] = wsum[0] + wsum[1] + wsum[2] + wsum[3];
}

// P2: pure VALU issue — same instruction count shape, zero memory, x8
__global__ __launch_bounds__(256) void probe_valu(
    const float* __restrict__ ws, float* __restrict__ dump)
{
    const int b = blockIdx.x, tid = threadIdx.x;
    const int q = tid & 15, rg = tid >> 4;
    const int n0 = (b & 255 & 15) * NT + rg * RT, d0 = q * 4;
    const float4* __restrict__ mup =
        (const float4*)(ws + MU_OFF + ((b >> 8) * NSAMP + n0) * DIM + d0);
    float4 mu4[RT];
#pragma unroll
    for (int r = 0; r < RT; ++r) mu4[r] = mup[r * (DIM / 4)];
    float4 ps[RT];
#pragma unroll
    for (int r = 0; r < RT; ++r) ps[r] = make_float4(0.f, 0.f, 0.f, 0.f);
    float4 base = make_float4(mu4[0].x + 1.f, mu4[1].y + 2.f,
                              mu4[2].z + 3.f, mu4[3].w + 4.f);
#pragma unroll 1
    for (int it = 0; it < 8; ++it) {
#pragma unroll 8
        for (int j = 0; j < JC; ++j) {
            base.x = fmaf(base.x, 1.0000001f, 0.03125f);
            base.y = fmaf(base.y, 1.0000002f, 0.03125f);
            base.z = fmaf(base.z, 1.0000001f, 0.01563f);
            base.w = fmaf(base.w, 1.0000002f, 0.01563f);
#pragma unroll
            for (int r = 0; r < RT; ++r) {
                ps[r].x += fabsf(base.x - mu4[r].x);
                ps[r].y += fabsf(base.y - mu4[r].y);
                ps[r].z += fabsf(base.z - mu4[r].z);
                ps[r].w += fabsf(base.w - mu4[r].w);
            }
        }
    }
    float s = 0.f;
#pragma unroll
    for (int r = 0; r < RT; ++r)
        s += ps[r].x + ps[r].y + ps[r].z + ps[r].w;
#pragma unroll
    for (int off = 32; off > 0; off >>= 1) s += __shfl_down(s, off, 64);
    if (tid == 0) dump[b] = s;
}

// P3: LDS b128 stream, minimal VALU (4 adds per read), x16
__global__ __launch_bounds__(256) void probe_lds(
    const float* __restrict__ fea0, const float* __restrict__ fea1,
    const float* __restrict__ fea2, float* __restrict__ dump)
{
    const int b = blockIdx.x, layer = b >> 8, sub = b & 255;
    const int jc = sub >> 4, tid = threadIdx.x;
    const float* __restrict__ fr_p =
        (layer == 0) ? fea0 : (layer == 1) ? fea1 : fea2;
    const int q = tid & 15;

    __shared__ float4 fr[JC][DIM / 4];
    __shared__ float wsum[4];
    const float4* __restrict__ src = (const float4*)(fr_p + jc * JC * DIM);
#pragma unroll
    for (int t = 0; t < 4; ++t)
        ((float4*)fr)[tid + t * 256] = src[tid + t * 256];
    __syncthreads();

    float4 acc = make_float4(0.f, 0.f, 0.f, 0.f);
#pragma unroll 1
    for (int it = 0; it < 16; ++it) {
#pragma unroll 8
        for (int j = 0; j < JC; ++j) {
            const float4 f = fr[(5 * j + it) & 63][q];
            acc.x += f.x; acc.y += f.y; acc.z += f.z; acc.w += f.w;
        }
    }
    float s = acc.x + acc.y + acc.z + acc.w;
#pragma unroll
    for (int off = 32; off > 0; off >>= 1) s += __shfl_down(s, off, 64);
    if ((tid & 63) == 0) wsum[tid >> 6] = s;
    __syncthreads();
    if (tid == 0) dump[b] = wsum[0] + wsum[1] + wsum[2] + wsum[3];
}

// P4: same stream but straight from GLOBAL (L1/L2), no LDS, x8
__global__ __launch_bounds__(256) void probe_glob(
    const float* __restrict__ fea0, const float* __restrict__ fea1,
    const float* __restrict__ fea2, float* __restrict__ dump)
{
    const int b = blockIdx.x, layer = b >> 8, sub = b & 255;
    const int jc = sub >> 4, tid = threadIdx.x;
    const float* __restrict__ fr_p =
        (layer == 0) ? fea0 : (layer == 1) ? fea1 : fea2;
    const int q = tid & 15;
    const float4* __restrict__ g = (const float4*)(fr_p + jc * JC * DIM);

    float4 acc = make_float4(0.f, 0.f, 0.f, 0.f);
#pragma unroll 1
    for (int it = 0; it < 8; ++it) {
#pragma unroll 8
        for (int j = 0; j < JC; ++j) {
            const float4 f = g[((5 * j + it) & 63) * (DIM / 4) + q];
            acc.x += f.x; acc.y += f.y; acc.z += f.z; acc.w += f.w;
        }
    }
    float s = acc.x + acc.y + acc.z + acc.w;
#pragma unroll
    for (int off = 32; off > 0; off >>= 1) s += __shfl_down(s, off, 64);
    if (tid == 0) dump[b] = s;
}

// P5: pair loop at 2x occupancy (JC=32 tile, 1536 blocks), x16
__global__ __launch_bounds__(256) void probe_pair_hi(
    const float* __restrict__ fea0, const float* __restrict__ fea1,
    const float* __restrict__ fea2,
    const float* __restrict__ ws, float* __restrict__ dump)
{
    const int b = blockIdx.x, layer = b >> 9, sub = b & 511;
    const int ntile = sub & 15, jc = sub >> 4, tid = threadIdx.x;
    const float* __restrict__ fr_p =
        (layer == 0) ? fea0 : (layer == 1) ? fea1 : fea2;
    const int q = tid & 15, rg = tid >> 4;
    const int n0 = ntile * NT + rg * RT, d0 = q * 4;

    __shared__ float4 fr[32][DIM / 4];   // 8 KB
    __shared__ float wsum[4];
    const float4* __restrict__ src = (const float4*)(fr_p + jc * 32 * DIM);
#pragma unroll
    for (int t = 0; t < 2; ++t)
        ((float4*)fr)[tid + t * 256] = src[tid + t * 256];

    const float4* __restrict__ mup =
        (const float4*)(ws + MU_OFF + (layer * NSAMP + n0) * DIM + d0);
    float4 mu4[RT];
#pragma unroll
    for (int r = 0; r < RT; ++r) mu4[r] = mup[r * (DIM / 4)];
    float4 ps[RT];
#pragma unroll
    for (int r = 0; r < RT; ++r) ps[r] = make_float4(0.f, 0.f, 0.f, 0.f);

    __syncthreads();
#pragma unroll 1
    for (int it = 0; it < 16; ++it) {
#pragma unroll 8
        for (int j = 0; j < 32; ++j) {
            const float4 f = fr[(j + it * 5) & 31][q];
#pragma unroll
            for (int r = 0; r < RT; ++r) {
                ps[r].x += fabsf(f.x - mu4[r].x);
                ps[r].y += fabsf(f.y - mu4[r].y);
                ps[r].z += fabsf(f.z - mu4[r].z);
                ps[r].w += fabsf(f.w - mu4[r].w);
            }
        }
    }
    float s = 0.f;
#pragma unroll
    for (int r = 0; r < RT; ++r)
        s += ps[r].x + ps[r].y + ps[r].z + ps[r].w;
#pragma unroll
    for (int off = 32; off > 0; off >>= 1) s += __shfl_down(s, off, 64);
    if ((tid & 63) == 0) wsum[tid >> 6] = s;
    __syncthreads();
    if (tid == 0) dump[b] = wsum[0] + wsum[1] + wsum[2] + wsum[3];
}

// ---------------------------------------------------------------------------
// fallback path (tiny ws): fused kernel + final reduce
__global__ __launch_bounds__(256) void ib_fused(
    const float* __restrict__ fea0, const float* __restrict__ fea1,
    const float* __restrict__ fea2, const float* __restrict__ fea3,
    const float* __restrict__ W_mu, const float* __restrict__ b_mu,
    const float* __restrict__ W_var, const float* __restrict__ b_var,
    float* __restrict__ partials)
{
    const int layer = blockIdx.y;
    const float* feas[4] = {fea0, fea1, fea2, fea3};
    const float* __restrict__ fr_p = feas[layer];
    const float* __restrict__ fs_p = feas[layer + 1];

    const int tid = threadIdx.x;
    const int d   = tid & 63;
    const int nl  = tid >> 6;
    const int n   = blockIdx.x * 4 + nl;

    __shared__ float fs[4][DIM];
    __shared__ float fr[64][DIM];
    __shared__ float wsum[4];

    fs[nl][d] = fs_p[n * DIM + d];
    __syncthreads();

    const float* __restrict__ wm = W_mu + (layer * DIM + d) * DIM;
    const float* __restrict__ wv = W_var + (layer * DIM + d) * DIM;
    float am = 0.f, av = 0.f;
#pragma unroll
    for (int k = 0; k < DIM; ++k) {
        const float f = fs[nl][k];
        am = fmaf(f, wm[k], am);
        av = fmaf(f, wv[k], av);
    }
    const float mu = am + b_mu[layer * DIM + d];
    const float x  = av + b_var[layer * DIM + d];
    const float sp  = fmaxf(x, 0.f) + log1pf(expf(-fabsf(x)));
    const float var = sp * 0.1f + 1e-6f;

    float psum = 0.f;
    for (int j0 = 0; j0 < NSAMP; j0 += 64) {
        __syncthreads();
#pragma unroll
        for (int t = 0; t < 16; ++t) {
            const int l = tid + t * 256;
            fr[0][l] = fr_p[j0 * DIM + l];
        }
        __syncthreads();
#pragma unroll
        for (int j = 0; j < 64; ++j)
            psum += fabsf(fr[j][d] - mu);
    }

    const float frnd = fr_p[n * DIM + d];
    float t = (psum * (1.0f / NSAMP) - fabsf(mu - frnd)) / var;

#pragma unroll
    for (int off = 32; off > 0; off >>= 1)
        t += __shfl_down(t, off, 64);
    if ((tid & 63) == 0) wsum[tid >> 6] = t;
    __syncthreads();
    if (tid == 0)
        partials[blockIdx.y * gridDim.x + blockIdx.x] =
            wsum[0] + wsum[1] + wsum[2] + wsum[3];
}

__global__ __launch_bounds__(256) void ib_final(
    const float* __restrict__ partials, int np, float scale,
    float* __restrict__ out)
{
    const int tid = threadIdx.x;
    float s = 0.f;
    for (int i = tid; i < np; i += 256) s += partials[i];
#pragma unroll
    for (int off = 32; off > 0; off >>= 1)
        s += __shfl_down(s, off, 64);
    __shared__ float wsum[4];
    if ((tid & 63) == 0) wsum[tid >> 6] = s;
    __syncthreads();
    if (tid == 0) out[0] = (wsum[0] + wsum[1] + wsum[2] + wsum[3]) * scale;
}

// ---------------------------------------------------------------------------
extern "C" void kernel_launch(void* const* d_in, const int* in_sizes, int n_in,
                              void* d_out, int out_size, void* d_ws, size_t ws_size,
                              hipStream_t stream) {
    const float* fea0  = (const float*)d_in[0];
    const float* fea1  = (const float*)d_in[1];
    const float* fea2  = (const float*)d_in[2];
    const float* fea3  = (const float*)d_in[3];
    const float* W_mu  = (const float*)d_in[4];
    const float* b_mu  = (const float*)d_in[5];
    const float* W_var = (const float*)d_in[6];
    const float* b_var = (const float*)d_in[7];
    float* out = (float*)d_out;
    float* ws  = (float*)d_ws;

    if (ws_size >= WS_REQ) {
        // real path (proven round-6, 33.7 us)
        ib_head<<<dim3(NSAMP / 4, NLAYER), 256, 0, stream>>>(
            fea1, fea2, fea3, W_mu, b_mu, W_var, b_var, ws);
        ib_pairf<<<NBLK, 256, 0, stream>>>(
            fea0, fea1, fea2, ws, (u64*)(ws + SLOT_F), out);

        // diagnostic probes (amplified; results dumped, never read)
        if (ws_size >= WS_PROBE) {
            float* dp = ws + DUMP_F;
            probe_pair<<<NBLK, 256, 0, stream>>>(fea0, fea1, fea2, ws, dp);
            probe_valu<<<NBLK, 256, 0, stream>>>(ws, dp + 2048);
            probe_lds<<<NBLK, 256, 0, stream>>>(fea0, fea1, fea2, dp + 4096);
            probe_glob<<<NBLK, 256, 0, stream>>>(fea0, fea1, fea2, dp + 6144);
            probe_pair_hi<<<1536, 256, 0, stream>>>(fea0, fea1, fea2, ws,
                                                    dp + 8192);
        }
    } else {
        const int nblk = NSAMP / 4;
        ib_fused<<<dim3(nblk, NLAYER), 256, 0, stream>>>(
            fea0, fea1, fea2, fea3, W_mu, b_mu, W_var, b_var, ws);
        ib_final<<<1, 256, 0, stream>>>(ws, nblk * NLAYER,
                                        1.0f / (float)NSAMP, out);
    }
}

// Round 11
// 29.853 us; speedup vs baseline: 15.7698x; 15.7698x over previous
//
#include <hip/hip_runtime.h>
#include <math.h>

#define NSAMP 1024
#define DIM   64
#define NLAYER 3

#define JC 32                         // j per block
#define JS (NSAMP / JC)               // 32 j-chunks
#define NT 64                         // n rows per block tile
#define RT 4                          // n rows per thread
#define NTILES (NSAMP / NT)           // 16 n-tiles
#define NBLK (NTILES * JS * NLAYER)   // 1536 pair blocks (6/CU)

#define MAGIC_HI 0x5AFE600Du

// workspace layout (float units)
#define MU_OFF   0
#define INV_OFF  (NLAYER * NSAMP * DIM)        // 196608
#define SLOT_F   (2 * NLAYER * NSAMP * DIM)    // u64 slots start here (8B-aligned)
#define WS_REQ   ((size_t)SLOT_F * sizeof(float) + NBLK * sizeof(unsigned long long))

typedef unsigned long long u64;

// 2-instr |f-mu| accumulate: v_sub + v_add with abs() source modifier.
// (Probe R10: compiler codegen runs ~4.4 instr/elem; this forces 2.)
__device__ __forceinline__ void absacc(float& acc, float f, float m) {
    float d;
    asm("v_sub_f32 %1, %2, %3\n\t"
        "v_add_f32 %0, %0, abs(%1)"
        : "+v"(acc), "=&v"(d)
        : "v"(f), "v"(m));
}

// ---------------------------------------------------------------------------
// Dispatch 1: head precompute (proven round-2/6 kernel, verbatim).
__global__ __launch_bounds__(256) void ib_head(
    const float* __restrict__ f1, const float* __restrict__ f2,
    const float* __restrict__ f3,
    const float* __restrict__ W_mu, const float* __restrict__ b_mu,
    const float* __restrict__ W_var, const float* __restrict__ b_var,
    float* __restrict__ ws)
{
    const int layer = blockIdx.y;
    const float* __restrict__ fs_p = (layer == 0) ? f1 : (layer == 1) ? f2 : f3;

    const int tid = threadIdx.x;
    const int d   = tid & 63;
    const int nl  = tid >> 6;
    const int n   = blockIdx.x * 4 + nl;

    __shared__ float fs[4][DIM];
    fs[nl][d] = fs_p[n * DIM + d];
    __syncthreads();

    const float4* __restrict__ wm = (const float4*)(W_mu + (layer * DIM + d) * DIM);
    const float4* __restrict__ wv = (const float4*)(W_var + (layer * DIM + d) * DIM);
    float am = 0.f, av = 0.f;
#pragma unroll
    for (int k = 0; k < DIM / 4; ++k) {
        const float4 m4 = wm[k];
        const float4 v4 = wv[k];
        const float f0 = fs[nl][k * 4 + 0];
        const float f1v = fs[nl][k * 4 + 1];
        const float f2v = fs[nl][k * 4 + 2];
        const float f3v = fs[nl][k * 4 + 3];
        am = fmaf(f0, m4.x, am); am = fmaf(f1v, m4.y, am);
        am = fmaf(f2v, m4.z, am); am = fmaf(f3v, m4.w, am);
        av = fmaf(f0, v4.x, av); av = fmaf(f1v, v4.y, av);
        av = fmaf(f2v, v4.z, av); av = fmaf(f3v, v4.w, av);
    }
    const float mu = am + b_mu[layer * DIM + d];
    const float x  = av + b_var[layer * DIM + d];
    const float sp  = fmaxf(x, 0.f) + log1pf(expf(-fabsf(x)));
    const float var = sp * 0.1f + 1e-6f;

    const int o = (layer * NSAMP + n) * DIM + d;
    ws[MU_OFF + o]  = mu;
    ws[INV_OFF + o] = 1.0f / var;
}

// ---------------------------------------------------------------------------
// Dispatch 2: pairwise, NO LDS (direct L1 reads), asm inner body, 1536 blocks.
// Finish: proven MAGIC-slot scheme (block 0 completion-poll, reduce, reset).
__global__ __launch_bounds__(256, 6) void ib_paird(
    const float* __restrict__ fea0, const float* __restrict__ fea1,
    const float* __restrict__ fea2,
    const float* __restrict__ ws, u64* __restrict__ slots,
    float* __restrict__ out)
{
    const int b     = blockIdx.x;          // 0..1535
    const int layer = b >> 9;              // 512 blocks per layer
    const int sub   = b & 511;
    const int ntile = sub & 15;
    const int jc    = sub >> 4;            // 0..31
    const int tid   = threadIdx.x;

    const float* __restrict__ fr_p =
        (layer == 0) ? fea0 : (layer == 1) ? fea1 : fea2;

    const int q  = tid & 15;
    const int rg = tid >> 4;
    const int n0 = ntile * NT + rg * RT;
    const int d0 = q * 4;

    // mu for my 4 rows (produced by previous dispatch; L2-resident)
    const float4* __restrict__ mup =
        (const float4*)(ws + MU_OFF + (layer * NSAMP + n0) * DIM + d0);
    float4 mu4[RT];
#pragma unroll
    for (int r = 0; r < RT; ++r) mu4[r] = mup[r * (DIM / 4)];

    float4 ps[RT];
#pragma unroll
    for (int r = 0; r < RT; ++r) ps[r] = make_float4(0.f, 0.f, 0.f, 0.f);

    // direct global reads: wave reads 16 distinct float4 per j (L1-resident)
    const float4* __restrict__ frj =
        (const float4*)(fr_p + jc * JC * DIM) + q;
#pragma unroll 4
    for (int j = 0; j < JC; ++j) {
        const float4 f = frj[j * (DIM / 4)];
#pragma unroll
        for (int r = 0; r < RT; ++r) {
            absacc(ps[r].x, f.x, mu4[r].x);
            absacc(ps[r].y, f.y, mu4[r].y);
            absacc(ps[r].z, f.z, mu4[r].z);
            absacc(ps[r].w, f.w, mu4[r].w);
        }
    }

    const float4* __restrict__ ivp =
        (const float4*)(ws + INV_OFF + (layer * NSAMP + n0) * DIM + d0);
    const float inv_n = 1.0f / (float)NSAMP;
    float s = 0.f;
    if (jc == 0) {
        // positive term exactly once per (n,d)
        const float4* __restrict__ fsp = (const float4*)(fr_p + n0 * DIM + d0);
#pragma unroll
        for (int r = 0; r < RT; ++r) {
            const float4 iv = ivp[r * (DIM / 4)];
            const float4 a  = fsp[r * (DIM / 4)];
            s += (ps[r].x * inv_n - fabsf(mu4[r].x - a.x)) * iv.x;
            s += (ps[r].y * inv_n - fabsf(mu4[r].y - a.y)) * iv.y;
            s += (ps[r].z * inv_n - fabsf(mu4[r].z - a.z)) * iv.z;
            s += (ps[r].w * inv_n - fabsf(mu4[r].w - a.w)) * iv.w;
        }
    } else {
#pragma unroll
        for (int r = 0; r < RT; ++r) {
            const float4 iv = ivp[r * (DIM / 4)];
            s += ps[r].x * inv_n * iv.x;
            s += ps[r].y * inv_n * iv.y;
            s += ps[r].z * inv_n * iv.z;
            s += ps[r].w * inv_n * iv.w;
        }
    }

    // deterministic block reduction
    __shared__ float wsum[4];
#pragma unroll
    for (int off = 32; off > 0; off >>= 1)
        s += __shfl_down(s, off, 64);
    if ((tid & 63) == 0) wsum[tid >> 6] = s;
    __syncthreads();

    // one contention-free 8B MAGIC store per block (own slot)
    if (tid == 0) {
        const float p = wsum[0] + wsum[1] + wsum[2] + wsum[3];
        const u64 v = ((u64)MAGIC_HI << 32) | (u64)__float_as_uint(p);
        __hip_atomic_store(&slots[b], v, __ATOMIC_RELAXED,
                           __HIP_MEMORY_SCOPE_AGENT);
    }

    // block 0: completion-only wait (safe), fixed-order reduce, reset slots
    if (b == 0) {
        __syncthreads();
        u64 v[6];
#pragma unroll
        for (int t = 0; t < 6; ++t) {
            u64* slot = &slots[tid + t * 256];
            for (;;) {
                const u64 x = __hip_atomic_load(slot, __ATOMIC_RELAXED,
                                                __HIP_MEMORY_SCOPE_AGENT);
                if ((unsigned)(x >> 32) == MAGIC_HI) { v[t] = x; break; }
                __builtin_amdgcn_s_sleep(1);
            }
        }
#pragma unroll
        for (int t = 0; t < 6; ++t)
            __hip_atomic_store(&slots[tid + t * 256], 0ull, __ATOMIC_RELAXED,
                               __HIP_MEMORY_SCOPE_AGENT);
        float s2 = 0.f;
#pragma unroll
        for (int t = 0; t < 6; ++t)
            s2 += __uint_as_float((unsigned)v[t]);
#pragma unroll
        for (int off = 32; off > 0; off >>= 1)
            s2 += __shfl_down(s2, off, 64);
        if ((tid & 63) == 0) wsum[tid >> 6] = s2;
        __syncthreads();
        if (tid == 0)
            out[0] = (wsum[0] + wsum[1] + wsum[2] + wsum[3]) * inv_n;
    }
}

// ---------------------------------------------------------------------------
// fallback path (tiny ws): fused kernel + final reduce
__global__ __launch_bounds__(256) void ib_fused(
    const float* __restrict__ fea0, const float* __restrict__ fea1,
    const float* __restrict__ fea2, const float* __restrict__ fea3,
    const float* __restrict__ W_mu, const float* __restrict__ b_mu,
    const float* __restrict__ W_var, const float* __restrict__ b_var,
    float* __restrict__ partials)
{
    const int layer = blockIdx.y;
    const float* feas[4] = {fea0, fea1, fea2, fea3};
    const float* __restrict__ fr_p = feas[layer];
    const float* __restrict__ fs_p = feas[layer + 1];

    const int tid = threadIdx.x;
    const int d   = tid & 63;
    const int nl  = tid >> 6;
    const int n   = blockIdx.x * 4 + nl;

    __shared__ float fs[4][DIM];
    __shared__ float fr[64][DIM];
    __shared__ float wsum[4];

    fs[nl][d] = fs_p[n * DIM + d];
    __syncthreads();

    const float* __restrict__ wm = W_mu + (layer * DIM + d) * DIM;
    const float* __restrict__ wv = W_var + (layer * DIM + d) * DIM;
    float am = 0.f, av = 0.f;
#pragma unroll
    for (int k = 0; k < DIM; ++k) {
        const float f = fs[nl][k];
        am = fmaf(f, wm[k], am);
        av = fmaf(f, wv[k], av);
    }
    const float mu = am + b_mu[layer * DIM + d];
    const float x  = av + b_var[layer * DIM + d];
    const float sp  = fmaxf(x, 0.f) + log1pf(expf(-fabsf(x)));
    const float var = sp * 0.1f + 1e-6f;

    float psum = 0.f;
    for (int j0 = 0; j0 < NSAMP; j0 += 64) {
        __syncthreads();
#pragma unroll
        for (int t = 0; t < 16; ++t) {
            const int l = tid + t * 256;
            fr[0][l] = fr_p[j0 * DIM + l];
        }
        __syncthreads();
#pragma unroll
        for (int j = 0; j < 64; ++j)
            psum += fabsf(fr[j][d] - mu);
    }

    const float frnd = fr_p[n * DIM + d];
    float t = (psum * (1.0f / NSAMP) - fabsf(mu - frnd)) / var;

#pragma unroll
    for (int off = 32; off > 0; off >>= 1)
        t += __shfl_down(t, off, 64);
    if ((tid & 63) == 0) wsum[tid >> 6] = t;
    __syncthreads();
    if (tid == 0)
        partials[blockIdx.y * gridDim.x + blockIdx.x] =
            wsum[0] + wsum[1] + wsum[2] + wsum[3];
}

__global__ __launch_bounds__(256) void ib_final(
    const float* __restrict__ partials, int np, float scale,
    float* __restrict__ out)
{
    const int tid = threadIdx.x;
    float s = 0.f;
    for (int i = tid; i < np; i += 256) s += partials[i];
#pragma unroll
    for (int off = 32; off > 0; off >>= 1)
        s += __shfl_down(s, off, 64);
    __shared__ float wsum[4];
    if ((tid & 63) == 0) wsum[tid >> 6] = s;
    __syncthreads();
    if (tid == 0) out[0] = (wsum[0] + wsum[1] + wsum[2] + wsum[3]) * scale;
}

// ---------------------------------------------------------------------------
extern "C" void kernel_launch(void* const* d_in, const int* in_sizes, int n_in,
                              void* d_out, int out_size, void* d_ws, size_t ws_size,
                              hipStream_t stream) {
    const float* fea0  = (const float*)d_in[0];
    const float* fea1  = (const float*)d_in[1];
    const float* fea2  = (const float*)d_in[2];
    const float* fea3  = (const float*)d_in[3];
    const float* W_mu  = (const float*)d_in[4];
    const float* b_mu  = (const float*)d_in[5];
    const float* W_var = (const float*)d_in[6];
    const float* b_var = (const float*)d_in[7];
    float* out = (float*)d_out;
    float* ws  = (float*)d_ws;

    if (ws_size >= WS_REQ) {
        ib_head<<<dim3(NSAMP / 4, NLAYER), 256, 0, stream>>>(
            fea1, fea2, fea3, W_mu, b_mu, W_var, b_var, ws);
        ib_paird<<<NBLK, 256, 0, stream>>>(
            fea0, fea1, fea2, ws, (u64*)(ws + SLOT_F), out);
    } else {
        const int nblk = NSAMP / 4;
        ib_fused<<<dim3(nblk, NLAYER), 256, 0, stream>>>(
            fea0, fea1, fea2, fea3, W_mu, b_mu, W_var, b_var, ws);
        ib_final<<<1, 256, 0, stream>>>(ws, nblk * NLAYER,
                                        1.0f / (float)NSAMP, out);
    }
}